// Round 2
// 729.547 us; speedup vs baseline: 1.1294x; 1.1294x over previous
//
#include <hip/hip_runtime.h>
#include <stdint.h>

// ---- static problem configuration ----
#define NRES    500
#define SKIPRES 4
#define PCOUNT  123256          // number of (i,j) pairs = triu(500, k=4)
#define NSYS    4
#define NW      52
#define BATCH   256
#define NB      4               // batch rows per thread (table path)

// ws layout:
//   float ws[0..3]          : 1/max_a[s]
//   (float4*)(ws+4)[0..499] : v[r][s] = 5*w[r][s]            (header = 8016 B)
//   byte 8192               : float4 atab[PCOUNT]  alpha
//   byte 8192 + P*16        : float4 ctab[PCOUNT]  (1-alpha/max)*0.5*sqrt2
//   byte 8192 + 2*P*16      : float2 ntab[PCOUNT]  (-mean/std, 1/std)

// ============================================================
// Kernel A: tiny prep — softmax -> v[r][s] = 5*w[r][s], 1/max_a
// ============================================================
__global__ void prep_kernel(const float* __restrict__ weights,
                            float* __restrict__ ws) {
    __shared__ float pbuf[NSYS][NW];
    __shared__ float vsh[NRES][NSYS];
    const int tid = threadIdx.x;

    if (tid < NSYS) {
        const int s = tid;
        float m = -1e30f;
        for (int k = 0; k < NW; ++k) m = fmaxf(m, weights[s * NW + k]);
        float sum = 0.f;
        for (int k = 0; k < NW; ++k) {
            float e = expf(weights[s * NW + k] - m);
            pbuf[s][k] = e;
            sum += e;
        }
        float scale = (float)NW / sum;   // softmax * NUM_WEIGHTS
        for (int k = 0; k < NW; ++k) pbuf[s][k] *= scale;
    }
    __syncthreads();

    for (int r = tid; r < NRES; r += blockDim.x) {
        const int st = r / 10;           // BALANCE = 0, SKIP = 10
        float a[NSYS];
        float denom = 2.5f;              // relu(FACTOR_FAKE - CUTOFF)
        for (int s = 0; s < NSYS; ++s) {
            float wr = pbuf[s][st] * pbuf[s][st + 1] * pbuf[s][st + 2];
            float t = wr - 0.5f;
            t = t > 0.f ? t : 0.f;
            a[s] = t;
            denom += t;
        }
        const float inv = 1.0f / denom;
        for (int s = 0; s < NSYS; ++s) vsh[r][s] = 5.0f * a[s] * inv;
    }
    __syncthreads();

    if (tid < NSYS) {
        const int s = tid;
        // max over pairs (i, j>=i+4) of v_i * v_j  via suffix max
        float m = 0.f, best = 0.f;
        for (int i = NRES - 1 - SKIPRES; i >= 0; --i) {
            m = fmaxf(m, vsh[i + SKIPRES][s]);
            best = fmaxf(best, vsh[i][s] * m);
        }
        ws[s] = 1.0f / best;
    }
    float4* vout = (float4*)(ws + 4);
    for (int r = tid; r < NRES; r += blockDim.x) {
        vout[r] = make_float4(vsh[r][0], vsh[r][1], vsh[r][2], vsh[r][3]);
    }
}

// ============================================================
// Pair decode: p -> (i, j) of triu_indices(500, k=4)
// ============================================================
__device__ __forceinline__ void decode_pair(int p, int& oi, int& oj) {
    float disc = 246512.25f - 2.0f * (float)p;
    int i = (int)(496.5f - __fsqrt_rn(disc));
    if (i < 0) i = 0;
    if (i > NRES - SKIPRES - 1) i = NRES - SKIPRES - 1;
#define CUM(ii) (((ii) * (993 - (ii))) >> 1)
    while (i > 0 && p < CUM(i)) --i;
    while (i < NRES - SKIPRES - 1 && p >= CUM(i + 1)) ++i;
    oj = p - CUM(i) + i + SKIPRES;
#undef CUM
    oi = i;
}

// ============================================================
// Kernel A2: build per-pair tables (runs once, 123K threads)
// ============================================================
__global__ __launch_bounds__(256)
void table_kernel(const float* __restrict__ mean,
                  const float* __restrict__ stdv,
                  const float* __restrict__ ws,
                  float4* __restrict__ atab,
                  float4* __restrict__ ctab,
                  float2* __restrict__ ntab) {
    const int p = blockIdx.x * 256 + threadIdx.x;
    if (p >= PCOUNT) return;

    int i, j;
    decode_pair(p, i, j);

    const float4* v4 = (const float4*)(ws + 4);
    const float4 vi = v4[i];
    const float4 vj = v4[j];
    const float im0 = ws[0], im1 = ws[1], im2 = ws[2], im3 = ws[3];

    float4 a;
    a.x = vi.x * vj.x;
    a.y = vi.y * vj.y;
    a.z = vi.z * vj.z;
    a.w = vi.w * vj.w;

    // (1 - alpha/max_a) * NOISE * sqrt(2)   (sqrt2 of normal() folded in)
    const float K = 0.5f * 1.41421356237f;
    float4 c;
    c.x = fmaf(-a.x, im0, 1.0f) * K;
    c.y = fmaf(-a.y, im1, 1.0f) * K;
    c.z = fmaf(-a.z, im2, 1.0f) * K;
    c.w = fmaf(-a.w, im3, 1.0f) * K;

    atab[p] = a;
    ctab[p] = c;

    const float sd = stdv[p];
    const float ooSd = 1.0f / sd;
    ntab[p] = make_float2(-mean[p] * ooSd, ooSd);   // xn = fma(x, ooSd, -mu/sd)
}

// ============================================================
// Threefry-2x32, key = (0, 42)  (jax.random.key(42))
// Partitionable stream: bits[L] = out0 ^ out1 of block (L>>32, L&0xffffffff).
// Here L < 2^32, so c0 = 0 always.  (Byte-identical to verified version.)
// ============================================================
__device__ __forceinline__ uint32_t rotl32(uint32_t x, int d) {
    return (x << d) | (x >> (32 - d));   // -> v_alignbit_b32
}

__device__ __forceinline__ uint32_t tf_bits(uint32_t c1) {
    const uint32_t ks0 = 0u;
    const uint32_t ks1 = 42u;
    const uint32_t ks2 = 0x1BD11BDAu ^ 0u ^ 42u;
    uint32_t x0 = 0u + ks0;      // c0 = 0
    uint32_t x1 = c1 + ks1;
#define TF_RND(d) { x0 += x1; x1 = rotl32(x1, (d)); x1 ^= x0; }
    TF_RND(13) TF_RND(15) TF_RND(26) TF_RND(6)
    x0 += ks1; x1 += ks2 + 1u;
    TF_RND(17) TF_RND(29) TF_RND(16) TF_RND(24)
    x0 += ks2; x1 += ks0 + 2u;
    TF_RND(13) TF_RND(15) TF_RND(26) TF_RND(6)
    x0 += ks0; x1 += ks1 + 3u;
    TF_RND(17) TF_RND(29) TF_RND(16) TF_RND(24)
    x0 += ks1; x1 += ks2 + 4u;
    TF_RND(13) TF_RND(15) TF_RND(26) TF_RND(6)
    x0 += ks2; x1 += ks0 + 5u;
#undef TF_RND
    return x0 ^ x1;              // partitionable 32-bit output
}

// uniform: f = bitcast(bits>>9 | 0x3F800000) - 1 in [0,1);
// u = max(lo, f*2 + lo)  — EXACT match to XLA (tail-sensitive, do not touch)
__device__ __forceinline__ float u_from_bits(uint32_t b) {
    const float lo = -0.99999994f;  // nextafterf(-1, 0)
    float f = __uint_as_float((b >> 9) | 0x3F800000u) - 1.0f;
    float u = fmaf(f, 2.0f, lo);
    return fmaxf(lo, u);
}

// XLA single-precision ErfInv (Giles polynomial) — byte-identical
__device__ __forceinline__ float erfinv_xla(float x) {
    float w = -__logf(1.0f - x * x);
    float p;
    if (w < 5.0f) {
        w = w - 2.5f;
        p =              2.81022636e-08f;
        p = fmaf(p, w,   3.43273939e-07f);
        p = fmaf(p, w,  -3.5233877e-06f);
        p = fmaf(p, w,  -4.39150654e-06f);
        p = fmaf(p, w,   0.00021858087f);
        p = fmaf(p, w,  -0.00125372503f);
        p = fmaf(p, w,  -0.00417768164f);
        p = fmaf(p, w,   0.246640727f);
        p = fmaf(p, w,   1.50140941f);
    } else {
        w = __fsqrt_rn(w) - 3.0f;
        p =             -0.000200214257f;
        p = fmaf(p, w,   0.000100950558f);
        p = fmaf(p, w,   0.00134934322f);
        p = fmaf(p, w,  -0.00367342844f);
        p = fmaf(p, w,   0.00573950773f);
        p = fmaf(p, w,  -0.0076224613f);
        p = fmaf(p, w,   0.00943887047f);
        p = fmaf(p, w,   1.00167406f);
        p = fmaf(p, w,   2.83297682f);
    }
    return p * x;
}

__device__ __forceinline__ float normal_from_bits(uint32_t b) {
    return 1.41421356237f * erfinv_xla(u_from_bits(b));  // fallback path only
}

// ============================================================
// Kernel B (table path): one thread = one pair p, NB batch rows.
// All per-pair math precomputed; body = RNG + 2 fma per output.
// ============================================================
__global__ __launch_bounds__(256)
void mask_kernel_tab(const float* __restrict__ x,
                     const float4* __restrict__ atab,
                     const float4* __restrict__ ctab,
                     const float2* __restrict__ ntab,
                     float* __restrict__ out) {
    const int p = blockIdx.x * 256 + threadIdx.x;
    if (p >= PCOUNT) return;

    const float4 a = atab[p];
    const float4 c = ctab[p];      // includes NOISE * sqrt(2)
    const float2 nr = ntab[p];     // (-mu/sd, 1/sd)

    uint32_t bp = (uint32_t)(blockIdx.y * NB) * (uint32_t)PCOUNT + (uint32_t)p;
    float4* o4 = (float4*)out;

#pragma unroll
    for (int k = 0; k < NB; ++k) {
        const float xn = fmaf(x[bp], nr.y, nr.x);
        const uint32_t base = bp * 4u;
        const float r0 = erfinv_xla(u_from_bits(tf_bits(base + 0u)));
        const float r1 = erfinv_xla(u_from_bits(tf_bits(base + 1u)));
        const float r2 = erfinv_xla(u_from_bits(tf_bits(base + 2u)));
        const float r3 = erfinv_xla(u_from_bits(tf_bits(base + 3u)));

        float4 o;
        o.x = fmaf(xn, a.x, c.x * r0);
        o.y = fmaf(xn, a.y, c.y * r1);
        o.z = fmaf(xn, a.z, c.z * r2);
        o.w = fmaf(xn, a.w, c.w * r3);
        o4[bp] = o;

        bp += (uint32_t)PCOUNT;
    }
}

// ============================================================
// Kernel B (fallback, ws too small): original monolithic version
// ============================================================
__global__ __launch_bounds__(256)
void mask_kernel(const float* __restrict__ x,
                 const float* __restrict__ mean,
                 const float* __restrict__ stdv,
                 const float* __restrict__ ws,
                 float* __restrict__ out) {
    const int p = blockIdx.x * 256 + threadIdx.x;
    if (p >= PCOUNT) return;
    const int b = blockIdx.y;

    int i, j;
    decode_pair(p, i, j);

    const float4* v4 = (const float4*)(ws + 4);
    const float4 vi = v4[i];
    const float4 vj = v4[j];
    const float im0 = ws[0], im1 = ws[1], im2 = ws[2], im3 = ws[3];

    const float a0 = vi.x * vj.x;
    const float a1 = vi.y * vj.y;
    const float a2 = vi.z * vj.z;
    const float a3 = vi.w * vj.w;
    const float c0 = fmaf(-a0, im0, 1.0f) * 0.5f;
    const float c1 = fmaf(-a1, im1, 1.0f) * 0.5f;
    const float c2 = fmaf(-a2, im2, 1.0f) * 0.5f;
    const float c3 = fmaf(-a3, im3, 1.0f) * 0.5f;

    const float mu = mean[p];
    const float sd = stdv[p];
    const uint32_t bp = (uint32_t)b * PCOUNT + (uint32_t)p;
    const float xn = (x[bp] - mu) / sd;

    const uint32_t base = bp * 4u;
    const float r0 = normal_from_bits(tf_bits(base + 0u));
    const float r1 = normal_from_bits(tf_bits(base + 1u));
    const float r2 = normal_from_bits(tf_bits(base + 2u));
    const float r3 = normal_from_bits(tf_bits(base + 3u));

    float4 o;
    o.x = fmaf(xn, a0, c0 * r0);
    o.y = fmaf(xn, a1, c1 * r1);
    o.z = fmaf(xn, a2, c2 * r2);
    o.w = fmaf(xn, a3, c3 * r3);

    ((float4*)out)[bp] = o;
}

// ============================================================
extern "C" void kernel_launch(void* const* d_in, const int* in_sizes, int n_in,
                              void* d_out, int out_size, void* d_ws, size_t ws_size,
                              hipStream_t stream) {
    const float* x       = (const float*)d_in[0];
    const float* mean    = (const float*)d_in[1];
    const float* stdv    = (const float*)d_in[2];
    const float* weights = (const float*)d_in[3];
    float* ws  = (float*)d_ws;
    float* out = (float*)d_out;

    hipLaunchKernelGGL(prep_kernel, dim3(1), dim3(256), 0, stream, weights, ws);

    const size_t ATAB_OFF = 8192;
    const size_t CTAB_OFF = ATAB_OFF + (size_t)PCOUNT * 16;
    const size_t NTAB_OFF = CTAB_OFF + (size_t)PCOUNT * 16;
    const size_t NEED     = NTAB_OFF + (size_t)PCOUNT * 8;

    const dim3 gx((PCOUNT + 255) / 256);

    if (ws_size >= NEED) {
        float4* atab = (float4*)((char*)d_ws + ATAB_OFF);
        float4* ctab = (float4*)((char*)d_ws + CTAB_OFF);
        float2* ntab = (float2*)((char*)d_ws + NTAB_OFF);

        hipLaunchKernelGGL(table_kernel, gx, dim3(256), 0, stream,
                           mean, stdv, ws, atab, ctab, ntab);

        dim3 grid(gx.x, BATCH / NB);
        hipLaunchKernelGGL(mask_kernel_tab, grid, dim3(256), 0, stream,
                           x, atab, ctab, ntab, out);
    } else {
        dim3 grid(gx.x, BATCH);
        hipLaunchKernelGGL(mask_kernel, grid, dim3(256), 0, stream,
                           x, mean, stdv, ws, out);
    }
}